// Round 14
// baseline (368.277 us; speedup 1.0000x reference)
//
#include <hip/hip_runtime.h>
#include <hip/hip_bf16.h>
#include <stdint.h>

#define B_   8
#define NS_  8192
#define E_   32
#define NT_  8192
#define NH_  10
#define NCH_ 128   // NS_/64 K-chunks
#define QCAP 128   // per-quarter candidate cap

typedef __bf16 bf16x8 __attribute__((ext_vector_type(8)));
typedef float  f32x4  __attribute__((ext_vector_type(4)));
typedef unsigned short ushort8_t __attribute__((ext_vector_type(8)));
typedef unsigned short ushort4_t __attribute__((ext_vector_type(4)));

static __device__ inline unsigned short f2bf(float f) {
  __hip_bfloat16 h = __float2bfloat16(f);
  return *reinterpret_cast<unsigned short*>(&h);
}
static __device__ inline float bf2f(unsigned short u) {
  __hip_bfloat16 h;
  *reinterpret_cast<unsigned short*>(&h) = u;
  return __bfloat162float(h);
}

// compile-time-constant vmcnt wait (constant-folds under full unroll)
static __device__ inline void wait_vm(int n) {
  switch (n) {
    case 0:  asm volatile("s_waitcnt vmcnt(0)" ::: "memory"); break;
    case 2:  asm volatile("s_waitcnt vmcnt(2)" ::: "memory"); break;
    case 4:  asm volatile("s_waitcnt vmcnt(4)" ::: "memory"); break;
    case 6:  asm volatile("s_waitcnt vmcnt(6)" ::: "memory"); break;
    case 8:  asm volatile("s_waitcnt vmcnt(8)" ::: "memory"); break;
    case 10: asm volatile("s_waitcnt vmcnt(10)" ::: "memory"); break;
    case 12: asm volatile("s_waitcnt vmcnt(12)" ::: "memory"); break;
    default: asm volatile("s_waitcnt vmcnt(14)" ::: "memory"); break;
  }
}

// 10th-smallest of the 64 per-lane values (lane-tagged u64 keys; exact).
static __device__ inline float tenth_smallest(float v, int lane) {
  unsigned long long kv =
      ((unsigned long long)__float_as_uint(v) << 32) | (unsigned)lane;
  float out = 0.f;
#pragma unroll
  for (int k = 0; k < NH_; ++k) {
    unsigned long long m = kv;
#pragma unroll
    for (int off = 32; off > 0; off >>= 1) {
      const unsigned long long o = __shfl_xor(m, off, 64);
      m = o < m ? o : m;
    }
    if (kv == m) kv = ~0ull;  // self-remove (unique by lane tag)
    if (k == NH_ - 1) out = __uint_as_float((unsigned)(m >> 32));
  }
  return out;
}

// ---------------------------------------------------------------------------
// Kernel A: per-target-row top-10 smallest d = sqrt(lon^2+lat^2).
// v14: async global_load_lds stream with counted vmcnt.
// r11-r13 post-mortem: compiler clamps register-load pipelines to ~2 in
// flight regardless of source structure (VGPR 24-44), and occupancy 49->78%
// left BW unchanged at 2.4 TB/s. global_load_lds + inline-asm vmcnt(N) is
// compiler-proof: each wave issues ALL 16 packet-loads (16 KB) upfront;
// per-CU in-flight ~128 KB >> latency-BW product.
//  Phase 1: p=0..7: vmcnt(14-2p); ds_read lon/lat; fma-d2 -> 32 regs; lmin.
//  T = 10th-smallest lane-min of WHOLE quarter (distinct-elements upper
//    bound, tighter than v13) * 1.000002 margin (fma-vs-strict + ties).
//  Phase 2: collect from register d2 (no re-reads).
//  Wave 0: VERIFIED exact machinery (strict-rn d, (d_bits<<32)|s key,
//  cascade + wave merge) — bit-identical to numpy incl. tie-breaking.
// ---------------------------------------------------------------------------
__global__ __launch_bounds__(256) void topk_kernel(
    const float* __restrict__ rel_lon, const float* __restrict__ rel_lat,
    float* __restrict__ out_d, float* __restrict__ out_lon,
    float* __restrict__ out_lat, int* __restrict__ idx_out)
{
  __shared__ __align__(16) float LonB[4][2048];  // 32 KB
  __shared__ __align__(16) float LatB[4][2048];  // 32 KB
  __shared__ int cnt[4];
  __shared__ unsigned int cand[4][QCAP];

  const int q = threadIdx.x >> 6;     // quarter index
  const int lane = threadIdx.x & 63;
  const int t = blockIdx.x;
  const float* lon_row = rel_lon + (size_t)t * NS_;
  const float* lat_row = rel_lat + (size_t)t * NS_;
  const int base = q * 2048;          // quarter element base
  const float* lonq = lon_row + base;
  const float* latq = lat_row + base;

  if (lane == 0) cnt[q] = 0;

  // ---- issue ALL 16 async loads (8 packets x {lon,lat}), 1 KB each ----
#pragma unroll
  for (int p = 0; p < 8; ++p) {
    __builtin_amdgcn_global_load_lds(
        (const __attribute__((address_space(1))) void*)(lonq + p * 256 +
                                                        lane * 4),
        (__attribute__((address_space(3))) void*)&LonB[q][p * 256], 16, 0, 0);
    __builtin_amdgcn_global_load_lds(
        (const __attribute__((address_space(1))) void*)(latq + p * 256 +
                                                        lane * 4),
        (__attribute__((address_space(3))) void*)&LatB[q][p * 256], 16, 0, 0);
  }

  // ---- phase 1: consume packets as they land; d2 -> registers ----
  float d2v[8][4];
  float lmin = __uint_as_float(0x7f800000u);  // +inf
#pragma unroll
  for (int p = 0; p < 8; ++p) {
    wait_vm(14 - 2 * p);   // packets 0..p landed; rest still in flight
    const float4 lo = *(const float4*)&LonB[q][p * 256 + lane * 4];
    const float4 la = *(const float4*)&LatB[q][p * 256 + lane * 4];
    d2v[p][0] = __fmaf_rn(lo.x, lo.x, __fmul_rn(la.x, la.x));
    d2v[p][1] = __fmaf_rn(lo.y, lo.y, __fmul_rn(la.y, la.y));
    d2v[p][2] = __fmaf_rn(lo.z, lo.z, __fmul_rn(la.z, la.z));
    d2v[p][3] = __fmaf_rn(lo.w, lo.w, __fmul_rn(la.w, la.w));
    lmin = fminf(lmin, fminf(fminf(d2v[p][0], d2v[p][1]),
                             fminf(d2v[p][2], d2v[p][3])));
  }

  // ---- quarter threshold (upper bound on quarter's 10th-smallest d2) ----
  const float T = tenth_smallest(lmin, lane) * 1.000002f;

  // ---- phase 2: collect candidates from register-resident d2 ----
#pragma unroll
  for (int p = 0; p < 8; ++p) {
    const float mn = fminf(fminf(d2v[p][0], d2v[p][1]),
                           fminf(d2v[p][2], d2v[p][3]));
    if (mn <= T) {  // rare
      const int s = base + p * 256 + lane * 4;
#pragma unroll
      for (int j = 0; j < 4; ++j) {
        if (d2v[p][j] <= T) {
          const int pos = atomicAdd(&cnt[q], 1);
          if (pos < QCAP) cand[q][pos] = (unsigned)(s + j);
        }
      }
    }
  }

  __syncthreads();

  // ---- wave 0: exact strict-d top-10 over merged candidates ----
  if (q == 0) {
    unsigned long long top[NH_];
#pragma unroll
    for (int i = 0; i < NH_; ++i) top[i] = ~0ull;

#pragma unroll
    for (int seg = 0; seg < 4; ++seg) {
      const int nc = min(cnt[seg], QCAP);
#pragma unroll
      for (int cc = 0; cc < QCAP / 64; ++cc) {
        const int ci = lane + cc * 64;
        if (ci < nc) {
          const unsigned s = cand[seg][ci];
          const float lo = lon_row[s];
          const float la = lat_row[s];
          // bit-exact numpy sequence: mul, mul, add, sqrt — all rn
          const float d = __fsqrt_rn(__fadd_rn(__fmul_rn(lo, lo),
                                               __fmul_rn(la, la)));
          unsigned long long p =
              ((unsigned long long)__float_as_uint(d) << 32) | s;
#pragma unroll
          for (int i = 0; i < NH_; ++i) {
            const bool lt = p < top[i];
            const unsigned long long mn2 = lt ? p : top[i];
            const unsigned long long mx2 = lt ? top[i] : p;
            top[i] = mn2;
            p = mx2;
          }
        }
      }
    }

    unsigned long long resv = ~0ull;
    unsigned long long cur = top[0];
#pragma unroll
    for (int k = 0; k < NH_; ++k) {
      unsigned long long m = cur;
#pragma unroll
      for (int off = 32; off > 0; off >>= 1) {
        const unsigned long long o = __shfl_xor(m, off, 64);
        m = o < m ? o : m;
      }
      if (cur == m) {
#pragma unroll
        for (int i = 0; i < NH_ - 1; ++i) top[i] = top[i + 1];
        top[NH_ - 1] = ~0ull;
        cur = top[0];
      }
      if (lane == k) resv = m;
    }

    if (lane < NH_) {
      const unsigned s = (unsigned)(resv & 0xffffffffu);
      const float d = __uint_as_float((unsigned)(resv >> 32));
      out_d[t * NH_ + lane] = d;
      idx_out[t * NH_ + lane] = (int)s;
      out_lon[t * NH_ + lane] = lon_row[s];
      out_lat[t * NH_ + lane] = lat_row[s];
    }
  }
}

// ---------------------------------------------------------------------------
// Kernel B: x_nearest gather. (VERIFIED PASSING — unchanged. Runs LAST.)
// ---------------------------------------------------------------------------
__global__ __launch_bounds__(256) void gather_kernel(
    const float* __restrict__ x, const int* __restrict__ idxbuf,
    float* __restrict__ out_xn)
{
  const int t = blockIdx.x;
  __shared__ int sidx[NH_];
  if (threadIdx.x < NH_) sidx[threadIdx.x] = idxbuf[t * NH_ + threadIdx.x];
  __syncthreads();
  for (int i = threadIdx.x; i < B_ * NH_ * (E_ / 4); i += 256) {  // 640 items
    const int e4 = i & 7;
    const int k = (i >> 3) % NH_;
    const int b = (i >> 3) / NH_;
    const int s = sidx[k];
    const float4 v = *(const float4*)(x + ((size_t)b * NS_ + s) * E_ + e4 * 4);
    *(float4*)(out_xn + (((size_t)b * NT_ + t) * NH_ + k) * E_ + e4 * 4) = v;
  }
}

// ---------------------------------------------------------------------------
// Kernel P: x (f32 [b][s][e]) -> XT2 (bf16, GEMM-chunked layout).
// (VERIFIED PASSING — unchanged.)
// ---------------------------------------------------------------------------
__global__ __launch_bounds__(256) void xprep_kernel(
    const float* __restrict__ x, unsigned short* __restrict__ XT2)
{
  __shared__ __align__(16) unsigned short T[32][136];
  const int b = blockIdx.y;
  const int s0 = blockIdx.x * 128;
  const int tid = threadIdx.x;
  const int eq = tid & 7, slq = tid >> 3;
#pragma unroll
  for (int r4 = 0; r4 < 4; ++r4) {
    const int sl = r4 * 32 + slq;
    const float4 v = *(const float4*)&x[((size_t)b * NS_ + s0 + sl) * E_ + eq * 4];
    T[eq * 4 + 0][sl] = f2bf(v.x);
    T[eq * 4 + 1][sl] = f2bf(v.y);
    T[eq * 4 + 2][sl] = f2bf(v.z);
    T[eq * 4 + 3][sl] = f2bf(v.w);
  }
  __syncthreads();
  const int r = tid & 31, cq = tid >> 5;
  const int be = b * 32 + r;
  const int sA = s0 + cq * 16;
  const int c = sA >> 6;
  const int kA = (sA >> 3) & 7;
  unsigned short* dst = XT2 + ((size_t)(c * 8 + kA) * 256 + be) * 8;
  *(ushort8_t*)dst = *(const ushort8_t*)&T[r][cq * 16];
  *(ushort8_t*)(dst + 2048) = *(const ushort8_t*)&T[r][cq * 16 + 8];
}

// ---------------------------------------------------------------------------
// Kernel C: x_inter via bf16 MFMA, double-buffered + shared B-fragments.
// (VERIFIED PASSING — unchanged.)
// ---------------------------------------------------------------------------
__global__ __launch_bounds__(512) void xinter_mfma(
    const unsigned short* __restrict__ XT2, const float* __restrict__ cs,
    const float* __restrict__ ct, float* __restrict__ out_xi)
{
#pragma clang fp contract(off)
  __shared__ __align__(16) unsigned short Xl[2][8][256][8];  // 64 KB
  __shared__ __align__(16) unsigned short Rl[2][8][16][8];   // 4 KB
  __shared__ float RsumP[16][32];
  __shared__ float RsumInv[32];

  const int tid = threadIdx.x;
  const int w = tid >> 6, l = tid & 63;
  const int mg = w >> 1, ng = w & 1;
  const int lcol = l & 15, lkg = l >> 4;
  const int t0 = blockIdx.x * 32;

  const int gt = tid & 31;
  const int gq = tid >> 5;
  const int gng = gt >> 4, glc = gt & 15;
  const int gk = gq >> 1;
  const int gsl = (gq & 1) * 4;
  const float2 ctg = ((const float2*)ct)[t0 + gt];
  const float t2g = ctg.x * ctg.x + ctg.y * ctg.y;   // strict rn
  float rpart = 0.f;

  const int t = t0 + ng * 16 + lcol;

  f32x4 acc[4];
#pragma unroll
  for (int m = 0; m < 4; ++m)
#pragma unroll
    for (int j = 0; j < 4; ++j) acc[m][j] = 0.f;

#define STAGE_CHUNK(buf, ch)                                                 \
  {                                                                          \
    const unsigned short* gsrc =                                             \
        XT2 + ((size_t)(ch) * 8 + w) * 2048 + (size_t)l * 8;                 \
    _Pragma("unroll")                                                        \
    for (int bg = 0; bg < 4; ++bg) {                                         \
      __builtin_amdgcn_global_load_lds(                                      \
          (const __attribute__((address_space(1))) void*)(gsrc + bg * 512),  \
          (__attribute__((address_space(3))) void*)&Xl[buf][w][bg * 64][0],  \
          16, 0, 0);                                                         \
    }                                                                        \
  }

  STAGE_CHUNK(0, 0);
  asm volatile("s_waitcnt vmcnt(0)" ::: "memory");
  __builtin_amdgcn_s_barrier();

  int cur = 0;
  for (int c = 0; c < NCH_; ++c) {
    if (c + 1 < NCH_) STAGE_CHUNK(cur ^ 1, c + 1);

    {
      const int sb = c * 64 + gq * 4;
      const float4 cA = *(const float4*)&cs[2 * sb];
      const float4 cB = *(const float4*)&cs[2 * sb + 4];
      const float sxv[4] = {cA.x, cA.z, cB.x, cB.z};
      const float syv[4] = {cA.y, cA.w, cB.y, cB.w};
      ushort4_t ro;
#pragma unroll
      for (int j = 0; j < 4; ++j) {
        const float sx = sxv[j], sy = syv[j];
        const float s2 = sx * sx + sy * sy;        // strict rn
        const float p0 = ctg.x * sx;               // strict rn product, k=0
        const float dot = fmaf(ctg.y, sy, p0);     // explicit fma, k=1
        const float ts = t2g + s2;                 // strict rn
        float d2 = ts - 2.0f * dot;                // 2*dot exact; strict sub
        d2 = fmaxf(d2, 1e-12f);
        const float r = __builtin_amdgcn_rsqf(d2);
        const unsigned short ub = f2bf(r);
        ro[j] = ub;
        rpart += bf2f(ub);
      }
      *(ushort4_t*)&Rl[gng][gk][glc][gsl] = ro;
    }
    asm volatile("s_waitcnt lgkmcnt(0)" ::: "memory");
    __builtin_amdgcn_s_barrier();

#pragma unroll
    for (int half = 0; half < 2; ++half) {
      const bf16x8 Bf = *(const bf16x8*)&Rl[ng][half * 4 + lkg][lcol][0];
#pragma unroll
      for (int m = 0; m < 4; ++m) {
        const bf16x8 a =
            *(const bf16x8*)&Xl[cur][half * 4 + lkg][(mg * 4 + m) * 16 + lcol][0];
        acc[m] = __builtin_amdgcn_mfma_f32_16x16x32_bf16(a, Bf, acc[m], 0, 0, 0);
      }
    }

    asm volatile("s_waitcnt vmcnt(0)" ::: "memory");
    __builtin_amdgcn_s_barrier();
    cur ^= 1;
  }
#undef STAGE_CHUNK

  RsumP[gq][gt] = rpart;
  asm volatile("s_waitcnt lgkmcnt(0)" ::: "memory");
  __builtin_amdgcn_s_barrier();
  if (tid < 32) {
    float ssum = 0.f;
#pragma unroll
    for (int qq = 0; qq < 16; ++qq) ssum += RsumP[qq][tid];
    RsumInv[tid] = 1.0f / ssum;
  }
  asm volatile("s_waitcnt lgkmcnt(0)" ::: "memory");
  __builtin_amdgcn_s_barrier();
  const float ri = RsumInv[ng * 16 + lcol];

#pragma unroll
  for (int m = 0; m < 4; ++m) {
    const int be0 = (mg * 4 + m) * 16 + lkg * 4;
    const int b = be0 >> 5, e = be0 & 31;
    float4 o;
    o.x = acc[m][0] * ri;
    o.y = acc[m][1] * ri;
    o.z = acc[m][2] * ri;
    o.w = acc[m][3] * ri;
    *(float4*)&out_xi[((size_t)b * NT_ + t) * E_ + e] = o;
  }
}

// ---------------------------------------------------------------------------
extern "C" void kernel_launch(void* const* d_in, const int* in_sizes, int n_in,
                              void* d_out, int out_size, void* d_ws,
                              size_t ws_size, hipStream_t stream)
{
  const float* x       = (const float*)d_in[0];
  const float* rel_lon = (const float*)d_in[1];
  const float* rel_lat = (const float*)d_in[2];
  const float* cs      = (const float*)d_in[3];
  const float* ct      = (const float*)d_in[4];

  float* out = (float*)d_out;
  float* out_xn  = out;                                // (8,8192,10,32)
  float* out_xi  = out + (size_t)B_ * NT_ * NH_ * E_;  // (8,8192,32)
  float* out_d   = out_xi + (size_t)B_ * NT_ * E_;     // (8192,10)
  float* out_lon = out_d + (size_t)NT_ * NH_;
  float* out_lat = out_lon + (size_t)NT_ * NH_;

  int* idxbuf = (int*)d_ws;                       // 328 KB
  unsigned short* XT2 = (unsigned short*)out_xn;  // 4 MB scratch in out_xn;
                                                  // gather_kernel rewrites it.

  topk_kernel<<<NT_, 256, 0, stream>>>(rel_lon, rel_lat, out_d, out_lon,
                                       out_lat, idxbuf);
  xprep_kernel<<<dim3(NS_ / 128, B_), 256, 0, stream>>>(x, XT2);
  xinter_mfma<<<NT_ / 32, 512, 0, stream>>>(XT2, cs, ct, out_xi);
  gather_kernel<<<NT_, 256, 0, stream>>>(x, idxbuf, out_xn);
}

// Round 15
// 254.578 us; speedup vs baseline: 1.4466x; 1.4466x over previous
//
#include <hip/hip_runtime.h>
#include <hip/hip_bf16.h>
#include <stdint.h>

#define B_   8
#define NS_  8192
#define E_   32
#define NT_  8192
#define NH_  10
#define NCH_ 128   // NS_/64 K-chunks
#define SCAP 128   // per-segment candidate cap (E~12 per 1024-elem segment)

typedef __bf16 bf16x8 __attribute__((ext_vector_type(8)));
typedef float  f32x4  __attribute__((ext_vector_type(4)));
typedef unsigned short ushort8_t __attribute__((ext_vector_type(8)));
typedef unsigned short ushort4_t __attribute__((ext_vector_type(4)));

static __device__ inline unsigned short f2bf(float f) {
  __hip_bfloat16 h = __float2bfloat16(f);
  return *reinterpret_cast<unsigned short*>(&h);
}
static __device__ inline float bf2f(unsigned short u) {
  __hip_bfloat16 h;
  *reinterpret_cast<unsigned short*>(&h) = u;
  return __bfloat162float(h);
}

// 10th-smallest of the 64 per-lane values (lane-tagged u64 keys; exact).
static __device__ inline float tenth_smallest(float v, int lane) {
  unsigned long long kv =
      ((unsigned long long)__float_as_uint(v) << 32) | (unsigned)lane;
  float out = 0.f;
#pragma unroll
  for (int k = 0; k < NH_; ++k) {
    unsigned long long m = kv;
#pragma unroll
    for (int off = 32; off > 0; off >>= 1) {
      const unsigned long long o = __shfl_xor(m, off, 64);
      m = o < m ? o : m;
    }
    if (kv == m) kv = ~0ull;  // self-remove (unique by lane tag)
    if (k == NH_ - 1) out = __uint_as_float((unsigned)(m >> 32));
  }
  return out;
}

// ---------------------------------------------------------------------------
// MEGA kernel: grid-level fusion of xinter (blocks 0..255, VALU/MFMA-bound,
// ~1% HBM) and topk (blocks 256..8447, HBM-bound, ~15% VALU). Disjoint
// pipes + no data dependency => co-resident overlap. xinter blocks first so
// each CU hosts ~1 xinter + 3 topk blocks (LDS 38.6KB/block => 4 blocks/CU,
// 32 waves). LDS is a union of the two paths' needs.
// ---------------------------------------------------------------------------
union __align__(16) SharedU {
  struct {
    unsigned short Xl[8][256][8];      // 32 KB (single-buffered A-tile)
    unsigned short Rl[2][8][16][8];    // 4 KB  (B-fragments, per-chunk)
    float RsumP[16][32];               // 2 KB
    float RsumInv[32];                 // 128 B
  } xi;
  struct {
    int cnt[8];
    unsigned int cand[8][SCAP];        // 4 KB
  } tk;
};

__global__ __launch_bounds__(512) void mega_kernel(
    const float* __restrict__ rel_lon, const float* __restrict__ rel_lat,
    float* __restrict__ out_d, float* __restrict__ out_lon,
    float* __restrict__ out_lat, int* __restrict__ idx_out,
    const unsigned short* __restrict__ XT2, const float* __restrict__ cs,
    const float* __restrict__ ct, float* __restrict__ out_xi)
{
#pragma clang fp contract(off)
  __shared__ SharedU sh;
  const int tid = threadIdx.x;

  if (blockIdx.x < 256) {
    // =====================================================================
    // xinter path (VERIFIED r8-r13 pipeline, single-buffered for LDS fit):
    //   out[be][t] = (sum_s XT[be][s] * r(t,s)) / rsum[t]
    // 8 waves = 4 mg x 2 ng; per chunk: stage A-tile (global_load_lds),
    // gen 32t x 64s r-tile once (strict bit-exact d2, r=rsq), MFMA.
    // =====================================================================
    const int w = tid >> 6, l = tid & 63;
    const int mg = w >> 1, ng = w & 1;
    const int lcol = l & 15, lkg = l >> 4;
    const int t0 = blockIdx.x * 32;

    const int gt = tid & 31;
    const int gq = tid >> 5;
    const int gng = gt >> 4, glc = gt & 15;
    const int gk = gq >> 1;
    const int gsl = (gq & 1) * 4;
    const float2 ctg = ((const float2*)ct)[t0 + gt];
    const float t2g = ctg.x * ctg.x + ctg.y * ctg.y;   // strict rn
    float rpart = 0.f;

    const int t = t0 + ng * 16 + lcol;

    f32x4 acc[4];
#pragma unroll
    for (int m = 0; m < 4; ++m)
#pragma unroll
      for (int j = 0; j < 4; ++j) acc[m][j] = 0.f;

    for (int c = 0; c < NCH_; ++c) {
      // ---- stage chunk c: wave w fills Xl[w][be][0..7] (coalesced) ----
      {
        const unsigned short* gsrc =
            XT2 + ((size_t)c * 8 + w) * 2048 + (size_t)l * 8;
#pragma unroll
        for (int bg = 0; bg < 4; ++bg) {
          __builtin_amdgcn_global_load_lds(
              (const __attribute__((address_space(1))) void*)(gsrc + bg * 512),
              (__attribute__((address_space(3))) void*)&sh.xi.Xl[w][bg * 64][0],
              16, 0, 0);
        }
      }
      // ---- gen r-tile (strict bit-exact d2 path; overlaps staging) ----
      {
        const int sb = c * 64 + gq * 4;
        const float4 cA = *(const float4*)&cs[2 * sb];
        const float4 cB = *(const float4*)&cs[2 * sb + 4];
        const float sxv[4] = {cA.x, cA.z, cB.x, cB.z};
        const float syv[4] = {cA.y, cA.w, cB.y, cB.w};
        ushort4_t ro;
#pragma unroll
        for (int j = 0; j < 4; ++j) {
          const float sx = sxv[j], sy = syv[j];
          const float s2 = sx * sx + sy * sy;        // strict rn
          const float p0 = ctg.x * sx;               // strict rn, k=0
          const float dot = fmaf(ctg.y, sy, p0);     // explicit fma, k=1
          const float ts = t2g + s2;                 // strict rn
          float d2 = ts - 2.0f * dot;                // 2*dot exact
          d2 = fmaxf(d2, 1e-12f);
          const float r = __builtin_amdgcn_rsqf(d2);
          const unsigned short ub = f2bf(r);
          ro[j] = ub;
          rpart += bf2f(ub);
        }
        *(ushort4_t*)&sh.xi.Rl[gng][gk][glc][gsl] = ro;
      }
      asm volatile("s_waitcnt vmcnt(0) lgkmcnt(0)" ::: "memory");
      __builtin_amdgcn_s_barrier();   // Xl + Rl ready for all waves

#pragma unroll
      for (int half = 0; half < 2; ++half) {
        const bf16x8 Bf = *(const bf16x8*)&sh.xi.Rl[ng][half * 4 + lkg][lcol][0];
#pragma unroll
        for (int m = 0; m < 4; ++m) {
          const bf16x8 a = *(const bf16x8*)
              &sh.xi.Xl[half * 4 + lkg][(mg * 4 + m) * 16 + lcol][0];
          acc[m] =
              __builtin_amdgcn_mfma_f32_16x16x32_bf16(a, Bf, acc[m], 0, 0, 0);
        }
      }
      __builtin_amdgcn_s_barrier();   // MFMA reads done before next overwrite
    }

    // ---- rsum reduction: 16 partials per t ----
    sh.xi.RsumP[gq][gt] = rpart;
    asm volatile("s_waitcnt lgkmcnt(0)" ::: "memory");
    __builtin_amdgcn_s_barrier();
    if (tid < 32) {
      float ssum = 0.f;
#pragma unroll
      for (int qq = 0; qq < 16; ++qq) ssum += sh.xi.RsumP[qq][tid];
      sh.xi.RsumInv[tid] = 1.0f / ssum;
    }
    asm volatile("s_waitcnt lgkmcnt(0)" ::: "memory");
    __builtin_amdgcn_s_barrier();
    const float ri = sh.xi.RsumInv[ng * 16 + lcol];

    // C/D layout: lane l reg j -> row(be) = lkg*4 + j, col(t) = lcol.
#pragma unroll
    for (int m = 0; m < 4; ++m) {
      const int be0 = (mg * 4 + m) * 16 + lkg * 4;
      const int b = be0 >> 5, e = be0 & 31;
      float4 o;
      o.x = acc[m][0] * ri;
      o.y = acc[m][1] * ri;
      o.z = acc[m][2] * ri;
      o.w = acc[m][3] * ri;
      *(float4*)&out_xi[((size_t)b * NT_ + t) * E_ + e] = o;
    }
  } else {
    // =====================================================================
    // topk path (r13 VERIFIED structure, 8 segments of 1024 elems):
    //  per wave: 4 packets -> d2 in regs; T = tenth_smallest(lane-min of
    //  whole segment) * 1.000002 (distinct-elements upper bound + margin);
    //  collect from register d2; wave 0 runs the exact strict-rn machinery
    //  (bit-identical to numpy incl. tie-breaking).
    // =====================================================================
    const int q = tid >> 6;       // segment index (0..7)
    const int lane = tid & 63;
    const int t = blockIdx.x - 256;
    const float* lon_row = rel_lon + (size_t)t * NS_;
    const float* lat_row = rel_lat + (size_t)t * NS_;
    const int base = q * 1024;
    const float4* lon4 = (const float4*)(lon_row + base);
    const float4* lat4 = (const float4*)(lat_row + base);

    if (lane == 0) sh.tk.cnt[q] = 0;

    float d2v[4][4];
    float lmin = __uint_as_float(0x7f800000u);  // +inf
#pragma unroll
    for (int p = 0; p < 4; ++p) {
      const float4 lo = lon4[p * 64 + lane];
      const float4 la = lat4[p * 64 + lane];
      d2v[p][0] = __fmaf_rn(lo.x, lo.x, __fmul_rn(la.x, la.x));
      d2v[p][1] = __fmaf_rn(lo.y, lo.y, __fmul_rn(la.y, la.y));
      d2v[p][2] = __fmaf_rn(lo.z, lo.z, __fmul_rn(la.z, la.z));
      d2v[p][3] = __fmaf_rn(lo.w, lo.w, __fmul_rn(la.w, la.w));
      lmin = fminf(lmin, fminf(fminf(d2v[p][0], d2v[p][1]),
                               fminf(d2v[p][2], d2v[p][3])));
    }
    const float T = tenth_smallest(lmin, lane) * 1.000002f;

#pragma unroll
    for (int p = 0; p < 4; ++p) {
      const float mn = fminf(fminf(d2v[p][0], d2v[p][1]),
                             fminf(d2v[p][2], d2v[p][3]));
      if (mn <= T) {  // rare
        const int s = base + p * 256 + lane * 4;
#pragma unroll
        for (int j = 0; j < 4; ++j) {
          if (d2v[p][j] <= T) {
            const int pos = atomicAdd(&sh.tk.cnt[q], 1);
            if (pos < SCAP) sh.tk.cand[q][pos] = (unsigned)(s + j);
          }
        }
      }
    }

    __syncthreads();

    // ---- wave 0: exact strict-d top-10 over merged candidates ----
    if (q == 0) {
      unsigned long long top[NH_];
#pragma unroll
      for (int i = 0; i < NH_; ++i) top[i] = ~0ull;

#pragma unroll
      for (int seg = 0; seg < 8; ++seg) {
        const int nc = min(sh.tk.cnt[seg], SCAP);
#pragma unroll
        for (int cc = 0; cc < SCAP / 64; ++cc) {
          const int ci = lane + cc * 64;
          if (ci < nc) {
            const unsigned s = sh.tk.cand[seg][ci];
            const float lo = lon_row[s];
            const float la = lat_row[s];
            // bit-exact numpy sequence: mul, mul, add, sqrt — all rn
            const float d = __fsqrt_rn(__fadd_rn(__fmul_rn(lo, lo),
                                                 __fmul_rn(la, la)));
            unsigned long long p =
                ((unsigned long long)__float_as_uint(d) << 32) | s;
#pragma unroll
            for (int i = 0; i < NH_; ++i) {
              const bool lt = p < top[i];
              const unsigned long long mn2 = lt ? p : top[i];
              const unsigned long long mx2 = lt ? top[i] : p;
              top[i] = mn2;
              p = mx2;
            }
          }
        }
      }

      unsigned long long resv = ~0ull;
      unsigned long long cur = top[0];
#pragma unroll
      for (int k = 0; k < NH_; ++k) {
        unsigned long long m = cur;
#pragma unroll
        for (int off = 32; off > 0; off >>= 1) {
          const unsigned long long o = __shfl_xor(m, off, 64);
          m = o < m ? o : m;
        }
        if (cur == m) {
#pragma unroll
          for (int i = 0; i < NH_ - 1; ++i) top[i] = top[i + 1];
          top[NH_ - 1] = ~0ull;
          cur = top[0];
        }
        if (lane == k) resv = m;
      }

      if (lane < NH_) {
        const unsigned s = (unsigned)(resv & 0xffffffffu);
        const float d = __uint_as_float((unsigned)(resv >> 32));
        out_d[t * NH_ + lane] = d;
        idx_out[t * NH_ + lane] = (int)s;
        out_lon[t * NH_ + lane] = lon_row[s];
        out_lat[t * NH_ + lane] = lat_row[s];
      }
    }
  }
}

// ---------------------------------------------------------------------------
// Kernel B: x_nearest gather. (VERIFIED PASSING — unchanged. Runs LAST.)
// ---------------------------------------------------------------------------
__global__ __launch_bounds__(256) void gather_kernel(
    const float* __restrict__ x, const int* __restrict__ idxbuf,
    float* __restrict__ out_xn)
{
  const int t = blockIdx.x;
  __shared__ int sidx[NH_];
  if (threadIdx.x < NH_) sidx[threadIdx.x] = idxbuf[t * NH_ + threadIdx.x];
  __syncthreads();
  for (int i = threadIdx.x; i < B_ * NH_ * (E_ / 4); i += 256) {  // 640 items
    const int e4 = i & 7;
    const int k = (i >> 3) % NH_;
    const int b = (i >> 3) / NH_;
    const int s = sidx[k];
    const float4 v = *(const float4*)(x + ((size_t)b * NS_ + s) * E_ + e4 * 4);
    *(float4*)(out_xn + (((size_t)b * NT_ + t) * NH_ + k) * E_ + e4 * 4) = v;
  }
}

// ---------------------------------------------------------------------------
// Kernel P: x (f32 [b][s][e]) -> XT2 (bf16, GEMM-chunked layout).
// (VERIFIED PASSING — unchanged.)
// ---------------------------------------------------------------------------
__global__ __launch_bounds__(256) void xprep_kernel(
    const float* __restrict__ x, unsigned short* __restrict__ XT2)
{
  __shared__ __align__(16) unsigned short T[32][136];
  const int b = blockIdx.y;
  const int s0 = blockIdx.x * 128;
  const int tid = threadIdx.x;
  const int eq = tid & 7, slq = tid >> 3;
#pragma unroll
  for (int r4 = 0; r4 < 4; ++r4) {
    const int sl = r4 * 32 + slq;
    const float4 v = *(const float4*)&x[((size_t)b * NS_ + s0 + sl) * E_ + eq * 4];
    T[eq * 4 + 0][sl] = f2bf(v.x);
    T[eq * 4 + 1][sl] = f2bf(v.y);
    T[eq * 4 + 2][sl] = f2bf(v.z);
    T[eq * 4 + 3][sl] = f2bf(v.w);
  }
  __syncthreads();
  const int r = tid & 31, cq = tid >> 5;
  const int be = b * 32 + r;
  const int sA = s0 + cq * 16;
  const int c = sA >> 6;
  const int kA = (sA >> 3) & 7;
  unsigned short* dst = XT2 + ((size_t)(c * 8 + kA) * 256 + be) * 8;
  *(ushort8_t*)dst = *(const ushort8_t*)&T[r][cq * 16];
  *(ushort8_t*)(dst + 2048) = *(const ushort8_t*)&T[r][cq * 16 + 8];
}

// ---------------------------------------------------------------------------
extern "C" void kernel_launch(void* const* d_in, const int* in_sizes, int n_in,
                              void* d_out, int out_size, void* d_ws,
                              size_t ws_size, hipStream_t stream)
{
  const float* x       = (const float*)d_in[0];
  const float* rel_lon = (const float*)d_in[1];
  const float* rel_lat = (const float*)d_in[2];
  const float* cs      = (const float*)d_in[3];
  const float* ct      = (const float*)d_in[4];

  float* out = (float*)d_out;
  float* out_xn  = out;                                // (8,8192,10,32)
  float* out_xi  = out + (size_t)B_ * NT_ * NH_ * E_;  // (8,8192,32)
  float* out_d   = out_xi + (size_t)B_ * NT_ * E_;     // (8192,10)
  float* out_lon = out_d + (size_t)NT_ * NH_;
  float* out_lat = out_lon + (size_t)NT_ * NH_;

  int* idxbuf = (int*)d_ws;                       // 328 KB
  unsigned short* XT2 = (unsigned short*)out_xn;  // 4 MB scratch in out_xn;
                                                  // gather_kernel rewrites it.

  xprep_kernel<<<dim3(NS_ / 128, B_), 256, 0, stream>>>(x, XT2);
  mega_kernel<<<256 + NT_, 512, 0, stream>>>(rel_lon, rel_lat, out_d, out_lon,
                                             out_lat, idxbuf, XT2, cs, ct,
                                             out_xi);
  gather_kernel<<<NT_, 256, 0, stream>>>(x, idxbuf, out_xn);
}